// Round 3
// baseline (1543.575 us; speedup 1.0000x reference)
//
#include <hip/hip_runtime.h>
#include <math.h>

#define WAYS 5
#define NQN 4096
#define NBATCH (NQN*WAYS)

// workspace float offsets
#define WS_SC 0         // 5*25*64 spt centered*rinv (l2-normalized) [w][i][c]
#define WS_RS 8000      // 125 inv l2 norms
#define WS_SP 8125      // 125 proj
#define WS_QM 8250      // 102400 qry per-token channel mean [q][j]
#define WS_QR 110650    // 102400 qry inv l2 norm
#define WS_TP 213050    // 102400 qry proj

__global__ void prep_spt(const float* __restrict__ spt, const float* __restrict__ proj_w,
                         const float* __restrict__ proj_b, float* __restrict__ ws) {
    int tid = threadIdx.x;
    if (tid >= 125) return;
    int w = tid / 25, i = tid % 25;
    const float* base = spt + w * 1600 + i;
    float s = 0.f;
    for (int c = 0; c < 64; c++) s += base[c * 25];
    float m = s * (1.f / 64.f);
    float ss = 0.f, pj = 0.f;
    for (int c = 0; c < 64; c++) {
        float v = base[c * 25] - m;
        ss += v * v; pj += v * proj_w[c];
    }
    float rinv = rsqrtf(ss + 1e-6f);
    for (int c = 0; c < 64; c++)
        ws[WS_SC + (w * 25 + i) * 64 + c] = (base[c * 25] - m) * rinv;
    ws[WS_RS + w * 25 + i] = rinv;
    ws[WS_SP + w * 25 + i] = pj + proj_b[0];
}

__global__ void prep_qry(const float* __restrict__ qry, const float* __restrict__ proj_w,
                         const float* __restrict__ proj_b, float* __restrict__ ws) {
    int idx = blockIdx.x * 256 + threadIdx.x;
    if (idx >= NQN * 25) return;
    int q = idx / 25, j = idx % 25;
    const float* base = qry + q * 1600 + j;
    float s = 0.f;
    for (int c = 0; c < 64; c++) s += base[c * 25];
    float m = s * (1.f / 64.f);
    float ss = 0.f, pj = 0.f;
    for (int c = 0; c < 64; c++) {
        float v = base[c * 25] - m;
        ss += v * v; pj += v * proj_w[c];
    }
    ws[WS_QM + idx] = m;
    ws[WS_QR + idx] = rsqrtf(ss + 1e-6f);
    ws[WS_TP + idx] = pj + proj_b[0];
}

// TC-thread tiled matmul: O[m*SO+n] {=|+=} act( sum_k A[m*SA+k]*W[n*WN+k] + bias[n] )
// Tiles iterated by TC threads; a small leftover tile-set (<= TC scalar outputs) is
// handled one-output-per-thread.
template<int M, int N, int K, int TM, int TN, int SA, int WN, int SO, int VW,
         bool ADD, bool GELU, int TC>
__device__ __forceinline__ void mmw(const float* __restrict__ A, const float* __restrict__ W,
                                    const float* __restrict__ bias, float* __restrict__ O,
                                    int tid) {
    static_assert(M % TM == 0 && N % TN == 0, "tile");
    static_assert(K % VW == 0, "vec");
    constexpr int GM = M / TM, GN = N / TN, ITEMS = GM * GN;
    constexpr int FULL = (ITEMS / TC) * TC;
    constexpr int REMO = (ITEMS - FULL) * TM * TN;
    constexpr bool SCT = (ITEMS > FULL) && (FULL > 0) && (REMO <= TC);
    constexpr int LIM = SCT ? FULL : ITEMS;

    for (int v = tid; v < LIM; v += TC) {
        const int m0 = (v / GN) * TM, n0 = (v % GN) * TN;
        float acc[TM][TN];
#pragma unroll
        for (int a = 0; a < TM; a++)
#pragma unroll
            for (int c = 0; c < TN; c++) acc[a][c] = 0.f;

        if constexpr (VW == 4) {
#pragma unroll
            for (int k = 0; k < K; k += 4) {
                float4 av[TM], wv[TN];
#pragma unroll
                for (int a = 0; a < TM; a++) av[a] = *(const float4*)(A + (m0 + a) * SA + k);
#pragma unroll
                for (int c = 0; c < TN; c++) wv[c] = *(const float4*)(W + (n0 + c) * WN + k);
#pragma unroll
                for (int a = 0; a < TM; a++)
#pragma unroll
                    for (int c = 0; c < TN; c++) {
                        acc[a][c] += av[a].x * wv[c].x;
                        acc[a][c] += av[a].y * wv[c].y;
                        acc[a][c] += av[a].z * wv[c].z;
                        acc[a][c] += av[a].w * wv[c].w;
                    }
            }
        } else {
#pragma unroll 4
            for (int k = 0; k < K; k += 2) {
                float2 av[TM], wv[TN];
#pragma unroll
                for (int a = 0; a < TM; a++) av[a] = *(const float2*)(A + (m0 + a) * SA + k);
#pragma unroll
                for (int c = 0; c < TN; c++) wv[c] = *(const float2*)(W + (n0 + c) * WN + k);
#pragma unroll
                for (int a = 0; a < TM; a++)
#pragma unroll
                    for (int c = 0; c < TN; c++) {
                        acc[a][c] += av[a].x * wv[c].x;
                        acc[a][c] += av[a].y * wv[c].y;
                    }
            }
        }
#pragma unroll
        for (int a = 0; a < TM; a++)
#pragma unroll
            for (int c = 0; c < TN; c++) {
                int n = n0 + c;
                float r = acc[a][c] + (bias ? bias[n] : 0.f);
                if (GELU) r = 0.5f * r * (1.f + erff(r * 0.70710678118654752f));
                if (ADD) O[(m0 + a) * SO + n] += r; else O[(m0 + a) * SO + n] = r;
            }
    }
    if constexpr (SCT) {
        if (tid < REMO) {
            const int t = FULL + tid / (TM * TN), r0 = tid % (TM * TN);
            const int m = (t / GN) * TM + r0 / TN, n = (t % GN) * TN + r0 % TN;
            float acc = 0.f;
#pragma unroll 4
            for (int k = 0; k < K; k += 2) {
                float2 a2 = *(const float2*)(A + m * SA + k);
                float2 w2 = *(const float2*)(W + n * WN + k);
                acc += a2.x * w2.x;
                acc += a2.y * w2.y;
            }
            float r = acc + (bias ? bias[n] : 0.f);
            if (GELU) r = 0.5f * r * (1.f + erff(r * 0.70710678118654752f));
            if (ADD) O[m * SO + n] += r; else O[m * SO + n] = r;
        }
    }
}

__device__ __forceinline__ void ln_row(const float* __restrict__ x, float* __restrict__ h,
                                       const float* __restrict__ g, const float* __restrict__ bb) {
    float s = 0.f;
#pragma unroll
    for (int e = 0; e < 26; e++) s += x[e];
    float m = s * (1.f / 26.f);
    float vv = 0.f;
#pragma unroll
    for (int e = 0; e < 26; e++) { float d = x[e] - m; vv += d * d; }
    float r = rsqrtf(vv * (1.f / 26.f) + 1e-6f);
#pragma unroll
    for (int e = 0; e < 26; e++) h[e] = (x[e] - m) * r * g[e] + bb[e];
}

// Two waves cooperate per (q,w) item; two items per 256-thread block.
// Per-item LDS region (4096 floats):
//   xm 0..650 | hm 650..1300 (ln out / oatt / asv,aqv) | corrm 1300..1925 (corr, later P_s / pooled)
//   sm 1925..1989 (qm[0..24], qr[32..56]) | scr 1992..4092 (phase union:
//     tcb[25][68]=1700 | qkv[25][78]=1950 (q@0,k@26,v@52; heads at +h*13) |
//     mlp-hid[25][52]=1300 | dec/refined 625 | qt 1600)
// LDS/block = 32 KB -> 4 blocks/CU -> 16 waves/CU (50%). VGPR cap 128 via launch_bounds.
__global__ void __launch_bounds__(256, 4)
fused_kernel(const float* __restrict__ qry, const float* __restrict__ ws,
             const float* __restrict__ pos_x, const float* __restrict__ pos_y,
             const float* __restrict__ qkv_w, const float* __restrict__ qkv_b,
             const float* __restrict__ attn_w, const float* __restrict__ attn_b,
             const float* __restrict__ ln1_g, const float* __restrict__ ln1_b,
             const float* __restrict__ ln2_g, const float* __restrict__ ln2_b,
             const float* __restrict__ fc1_w, const float* __restrict__ fc1_b,
             const float* __restrict__ fc2_w, const float* __restrict__ fc2_b,
             const float* __restrict__ dec_w, const float* __restrict__ dec_b,
             float* __restrict__ out) {
    __shared__ __align__(16) float lds[2][4096];
    const int half = threadIdx.x >> 7;            // item within block
    const int tid  = threadIdx.x & 127;           // 0..127 within item
    const int w2   = tid >> 6, lane = tid & 63;   // wave-in-item, lane
    const int b = blockIdx.x * 2 + half, q = b / WAYS, w = b % WAYS;

    float* xm    = lds[half];
    float* hm    = xm + 650;
    float* corrm = xm + 1300;
    float* sm    = xm + 1925;
    float* scr   = xm + 1992;

    // stage qm/qr for this q
    if (tid < 25) {
        sm[tid]      = ws[WS_QM + q * 25 + tid];
        sm[32 + tid] = ws[WS_QR + q * 25 + tid];
    }
    __syncthreads();

    // stage tcb = l2-normalized qry tokens, [j][68]
    for (int e = tid; e < 1600; e += 128) {
        int c = e / 25, j = e - c * 25;
        scr[j * 68 + c] = (qry[q * 1600 + e] - sm[j]) * sm[32 + j];
    }
    __syncthreads();

    // corr[i][j] = sn_i . tn_j  (A from global ws, L1/L2-resident 32KB) -> corrm
    mmw<25, 25, 64, 5, 1, 64, 68, 25, 4, false, false, 128>(ws + WS_SC + w * 1600, scr, nullptr, corrm, tid);
    __syncthreads();

    // x1: rows = qry tokens; [corr^T | tp] + pos
    for (int e = tid; e < 650; e += 128) {
        int t = e / 26, d = e - t * 26;
        float p = (d < 13) ? pos_x[(t % 5) * 13 + d] : pos_y[(t / 5) * 13 + (d - 13)];
        float base = (d < 25) ? corrm[d * 25 + t] : ws[WS_TP + q * 25 + t];
        xm[e] = base + p;
    }
    __syncthreads();

    for (int it = 0; it < 2; ++it) {
        // ln1: rows split 13/12 across the two waves
        { int r = w2 * 13 + lane; if (lane < 13 - w2) ln_row(xm + r * 26, hm + r * 26, ln1_g, ln1_b); }
        __syncthreads();
        // qkv single matmul, O[t*78 + n]: q@0..25, k@26..51, v@52..77 (head h at +h*13)
        mmw<25, 78, 26, 5, 3, 26, 26, 78, 2, false, false, 128>(hm, qkv_w, qkv_b, scr, tid);
        __syncthreads();
        // fused attention: wave w2 handles head h=w2; lane i<25 owns one score row in regs.
        // All 25 lanes of a head read the same k/v row address -> LDS broadcast.
        if (lane < 25) {
            const int h = w2, i = lane;
            const float* qb = scr + i * 78 + h * 13;
            float qv[13];
#pragma unroll
            for (int k = 0; k < 13; k++) qv[k] = qb[k];
            float P[25];
            float mx = -1e30f;
#pragma unroll
            for (int j = 0; j < 25; j++) {
                const float* kb = scr + j * 78 + 26 + h * 13;
                float a = 0.f;
#pragma unroll
                for (int k = 0; k < 13; k++) a += qv[k] * kb[k];
                a *= 0.27735009811261457f;   // 13^-0.5
                P[j] = a; mx = fmaxf(mx, a);
            }
            float s = 0.f;
#pragma unroll
            for (int j = 0; j < 25; j++) { P[j] = __expf(P[j] - mx); s += P[j]; }
            float inv = 1.f / s;
            float o[13];
#pragma unroll
            for (int n = 0; n < 13; n++) o[n] = 0.f;
#pragma unroll
            for (int k = 0; k < 25; k++) {
                const float* vb = scr + k * 78 + 52 + h * 13;
                float p = P[k];
#pragma unroll
                for (int n = 0; n < 13; n++) o[n] += p * vb[n];
            }
            float* ob = hm + i * 26 + h * 13;
#pragma unroll
            for (int n = 0; n < 13; n++) ob[n] = o[n] * inv;
        }
        __syncthreads();
        // attn proj + residual
        mmw<25, 26, 26, 5, 1, 26, 26, 26, 2, true, false, 128>(hm, attn_w, attn_b, xm, tid);
        __syncthreads();
        { int r = w2 * 13 + lane; if (lane < 13 - w2) ln_row(xm + r * 26, hm + r * 26, ln2_g, ln2_b); }
        __syncthreads();
        // MLP in two 52-wide halves (hidden kept in 1300 floats of scr)
        mmw<25, 52, 26, 5, 2, 26, 26, 52, 2, false, true, 128>(hm, fc1_w, fc1_b, scr, tid);
        __syncthreads();
        mmw<25, 26, 52, 5, 1, 52, 104, 26, 2, true, false, 128>(scr, fc2_w, fc2_b, xm, tid);
        __syncthreads();
        mmw<25, 52, 26, 5, 2, 26, 26, 52, 2, false, true, 128>(hm, fc1_w + 1352, fc1_b + 52, scr, tid);
        __syncthreads();
        mmw<25, 26, 52, 5, 1, 52, 104, 26, 2, true, false, 128>(scr, fc2_w + 52, nullptr, xm, tid);
        __syncthreads();
        // dec
        mmw<25, 25, 26, 5, 1, 26, 26, 25, 2, false, false, 128>(xm, dec_w, dec_b, scr, tid);
        __syncthreads();
        if (it == 0) {
            // x2: rows = spt tokens; [dec1^T + corr | sp] + pos
            for (int e = tid; e < 650; e += 128) {
                int t = e / 26, d = e - t * 26;
                float p = (d < 13) ? pos_x[(t % 5) * 13 + d] : pos_y[(t / 5) * 13 + (d - 13)];
                float base = (d < 25) ? (scr[d * 25 + t] + corrm[t * 25 + d]) : ws[WS_SP + w * 25 + t];
                xm[e] = base + p;
            }
            __syncthreads();
        }
    }

    // refined = dec2 + corr (in scr); corrm and xm are dead afterwards
    for (int e = tid; e < 625; e += 128) scr[e] += corrm[e];
    __syncthreads();

    // concurrent: wave0 -> attn_s (per column j, over i) into corrm;
    //             wave1 -> attn_q (per row i, over j) into xm
    if (lane < 25) {
        if (w2 == 0) {
            int j = lane;
            float s = 0.f;
            for (int i = 0; i < 25; i++) s += scr[i * 25 + j];
            float m = s * 0.04f;
            float ss = 0.f;
            for (int i = 0; i < 25; i++) { float d = scr[i * 25 + j] - m; ss += d * d; }
            float rinv = rsqrtf(ss * (1.f / 24.f) + 1e-5f) * 0.2f;   // /T_ATTN
            float mx = -1e30f;
            for (int i = 0; i < 25; i++) { float z = (scr[i * 25 + j] - m) * rinv; corrm[i * 25 + j] = z; mx = fmaxf(mx, z); }
            float se = 0.f;
            for (int i = 0; i < 25; i++) { float e2 = __expf(corrm[i * 25 + j] - mx); corrm[i * 25 + j] = e2; se += e2; }
            float inv = 1.f / se;
            for (int i = 0; i < 25; i++) corrm[i * 25 + j] *= inv;
        } else {
            int i = lane;
            float s = 0.f;
            for (int j = 0; j < 25; j++) s += scr[i * 25 + j];
            float m = s * 0.04f;
            float ss = 0.f;
            for (int j = 0; j < 25; j++) { float d = scr[i * 25 + j] - m; ss += d * d; }
            float rinv = rsqrtf(ss * (1.f / 24.f) + 1e-5f) * 0.2f;
            float mx = -1e30f;
            for (int j = 0; j < 25; j++) { float z = (scr[i * 25 + j] - m) * rinv; xm[i * 25 + j] = z; mx = fmaxf(mx, z); }
            float se = 0.f;
            for (int j = 0; j < 25; j++) { float e2 = __expf(xm[i * 25 + j] - mx); xm[i * 25 + j] = e2; se += e2; }
            float inv = 1.f / se;
            for (int j = 0; j < 25; j++) xm[i * 25 + j] *= inv;
        }
    }
    __syncthreads();
    if (lane < 25) {
        if (w2 == 0) {      // asv: row sums of P_s
            int i = lane; float s = 0.f;
            for (int j = 0; j < 25; j++) s += corrm[i * 25 + j];
            hm[i] = s * 0.04f / ws[WS_RS + w * 25 + i];
        } else {            // aqv: column sums of P_q
            int j = lane; float s = 0.f;
            for (int i = 0; i < 25; i++) s += xm[i * 25 + j];
            hm[32 + j] = s * 0.04f / sm[32 + j];
        }
    }
    __syncthreads();

    // re-stage normalized qry transposed [c][25] into scr (refined is dead)
    for (int e = tid; e < 1600; e += 128) {
        int c = e / 25, j = e - c * 25;
        scr[e] = (qry[q * 1600 + e] - sm[j]) * sm[32 + j];
    }
    __syncthreads();

    // pooled features per channel: wave0 -> sv, wave1 -> qv2 (lane = channel)
    if (w2 == 0) {
        float sv = 0.f;
        const float* snb = ws + WS_SC + w * 1600 + lane;
        for (int i = 0; i < 25; i++) sv += hm[i] * snb[i * 64];
        corrm[lane] = sv;
    } else {
        float qv2 = 0.f;
        for (int j = 0; j < 25; j++) qv2 += hm[32 + j] * scr[lane * 25 + j];
        corrm[64 + lane] = qv2;
    }
    __syncthreads();
    if (w2 == 0) {
        float a = corrm[lane], b2 = corrm[64 + lane];
        float d = a * b2, n1 = a * a, n2 = b2 * b2;
#pragma unroll
        for (int msk = 32; msk >= 1; msk >>= 1) {
            d  += __shfl_xor(d,  msk);
            n1 += __shfl_xor(n1, msk);
            n2 += __shfl_xor(n2, msk);
        }
        if (lane == 0) {
            n1 = fmaxf(sqrtf(n1), 1e-8f);
            n2 = fmaxf(sqrtf(n2), 1e-8f);
            out[b] = d / (n1 * n2) * 5.f;   // /TEMP
        }
    }
}

extern "C" void kernel_launch(void* const* d_in, const int* in_sizes, int n_in,
                              void* d_out, int out_size, void* d_ws, size_t ws_size,
                              hipStream_t stream) {
    const float* spt    = (const float*)d_in[0];
    const float* qry    = (const float*)d_in[1];
    const float* proj_w = (const float*)d_in[2];
    const float* proj_b = (const float*)d_in[3];
    const float* pos_x  = (const float*)d_in[4];
    const float* pos_y  = (const float*)d_in[5];
    const float* ln1_g  = (const float*)d_in[6];
    const float* ln1_b  = (const float*)d_in[7];
    const float* qkv_w  = (const float*)d_in[8];
    const float* qkv_b  = (const float*)d_in[9];
    const float* attn_w = (const float*)d_in[10];
    const float* attn_b = (const float*)d_in[11];
    const float* ln2_g  = (const float*)d_in[12];
    const float* ln2_b  = (const float*)d_in[13];
    const float* fc1_w  = (const float*)d_in[14];
    const float* fc1_b  = (const float*)d_in[15];
    const float* fc2_w  = (const float*)d_in[16];
    const float* fc2_b  = (const float*)d_in[17];
    const float* dec_w  = (const float*)d_in[18];
    const float* dec_b  = (const float*)d_in[19];
    float* ws  = (float*)d_ws;
    float* out = (float*)d_out;

    prep_spt<<<1, 128, 0, stream>>>(spt, proj_w, proj_b, ws);
    prep_qry<<<(NQN * 25 + 255) / 256, 256, 0, stream>>>(qry, proj_w, proj_b, ws);
    fused_kernel<<<NBATCH / 2, 256, 0, stream>>>(qry, ws, pos_x, pos_y, qkv_w, qkv_b, attn_w, attn_b,
                                                 ln1_g, ln1_b, ln2_g, ln2_b, fc1_w, fc1_b,
                                                 fc2_w, fc2_b, dec_w, dec_b, out);
}